// Round 6
// baseline (671.559 us; speedup 1.0000x reference)
//
#include <hip/hip_runtime.h>
#include <stdint.h>

// Problem constants (B=2, D_MODEL=256, C=64, T=1024, H=8, F=32)
// Inputs fp32, output fp32. Intermediates bf16. GEMMs on MFMA bf16.
#define D_MODEL 256
#define TDIM    1024
#define NHEADS  8
#define FDIM    32
#define P_LEN   65536      // C*T positions per batch
#define K3      768        // 3*D_MODEL
#define BK      64         // K-tile per LDS stage

using u16 = unsigned short;

typedef __bf16 bf16x8 __attribute__((ext_vector_type(8)));
typedef float  floatx4 __attribute__((ext_vector_type(4)));

__device__ __forceinline__ float b2f_lo(uint32_t u) {
    union { float f; uint32_t i; } v; v.i = u << 16; return v.f;
}
__device__ __forceinline__ float b2f_hi(uint32_t u) {
    union { float f; uint32_t i; } v; v.i = u & 0xffff0000u; return v.f;
}
__device__ __forceinline__ u16 f2b(float f) {
    union { float f; uint32_t i; } v; v.f = f;
    uint32_t i = v.i;
    uint32_t r = i + 0x7fffu + ((i >> 16) & 1u);   // RNE
    return (u16)(r >> 16);
}
__device__ __forceinline__ uint32_t pack2(float lo, float hi) {
    return ((uint32_t)f2b(hi) << 16) | (uint32_t)f2b(lo);
}

// async global->LDS, 16B per lane; lds base must be wave-uniform, lane i
// lands at base + i*16 (guide §5 / m97 / m104).
__device__ __forceinline__ void gload_lds16(const u16* g, u16* l) {
    __builtin_amdgcn_global_load_lds((const __attribute__((address_space(1))) void*)g,
                                     (__attribute__((address_space(3))) void*)l,
                                     16, 0, 0);
}

__device__ __forceinline__ void stc(u16* p, float v) { *p = f2b(v); }
__device__ __forceinline__ void stc(float* p, float v) { *p = v; }

// ---------------------------------------------------------------------------
// 1) Transpose + bf16 convert + InstanceNorm partial stats:
//    x[d][p] fp32 -> xt[p][d] bf16 (one batch); per-(d, blockIdx.x) partial
//    Sum/SumSq written contention-free to pscr/qscr[d][1024].
// ---------------------------------------------------------------------------
__global__ __launch_bounds__(256) void transpose_x(const float* __restrict__ x,
                                                   u16* __restrict__ xt,
                                                   float* __restrict__ pscr,
                                                   float* __restrict__ qscr) {
    __shared__ float tile[64][65];
    int p0 = blockIdx.x * 64;
    int d0 = blockIdx.y * 64;
    int tid = threadIdx.x;
    int dr = tid >> 4;            // 0..15
    int pc = (tid & 15) * 4;      // 0..60
#pragma unroll
    for (int it = 0; it < 4; ++it) {
        int d = it * 16 + dr;
        float4 v = *(const float4*)&x[(size_t)(d0 + d) * P_LEN + p0 + pc];
        tile[pc + 0][d] = v.x;
        tile[pc + 1][d] = v.y;
        tile[pc + 2][d] = v.z;
        tile[pc + 3][d] = v.w;
        // fused stats: 16 lanes (same dr) hold this row's 64 p-values
        float s = v.x + v.y + v.z + v.w;
        float sq = v.x * v.x + v.y * v.y + v.z * v.z + v.w * v.w;
#pragma unroll
        for (int off = 8; off; off >>= 1) {
            s  += __shfl_down(s, off, 16);
            sq += __shfl_down(sq, off, 16);
        }
        if ((tid & 15) == 0) {
            pscr[(size_t)(d0 + d) * 1024 + blockIdx.x] = s;
            qscr[(size_t)(d0 + d) * 1024 + blockIdx.x] = sq;
        }
    }
    __syncthreads();
    int pr = tid >> 3;            // 0..31
    int dc = (tid & 7) * 8;       // 0..56
#pragma unroll
    for (int it = 0; it < 2; ++it) {
        int p = it * 32 + pr;
        ushort4 o0 = make_ushort4(f2b(tile[p][dc + 0]), f2b(tile[p][dc + 1]),
                                  f2b(tile[p][dc + 2]), f2b(tile[p][dc + 3]));
        ushort4 o1 = make_ushort4(f2b(tile[p][dc + 4]), f2b(tile[p][dc + 5]),
                                  f2b(tile[p][dc + 6]), f2b(tile[p][dc + 7]));
        u16* dst = xt + (size_t)(p0 + p) * D_MODEL + d0 + dc;
        *(ushort4*)dst = o0;
        *(ushort4*)(dst + 4) = o1;
    }
}

// ---------------------------------------------------------------------------
// 2) Reduce partials -> mu/rstd. One wave per d, coalesced float4 reads.
// ---------------------------------------------------------------------------
__global__ __launch_bounds__(64) void reduce_stats(const float* __restrict__ pscr,
                                                   const float* __restrict__ qscr,
                                                   float* __restrict__ mu,
                                                   float* __restrict__ rstd) {
    int d = blockIdx.x, t = threadIdx.x;
    const float4* ps = (const float4*)(pscr + (size_t)d * 1024);
    const float4* qs = (const float4*)(qscr + (size_t)d * 1024);
    float s = 0.f, q = 0.f;
#pragma unroll
    for (int i = 0; i < 4; ++i) {
        float4 a = ps[t + i * 64]; s += a.x + a.y + a.z + a.w;
        float4 b = qs[t + i * 64]; q += b.x + b.y + b.z + b.w;
    }
    for (int off = 32; off; off >>= 1) {
        s += __shfl_down(s, off);
        q += __shfl_down(q, off);
    }
    if (t == 0) {
        float m = s * (1.f / 65536.f);
        float var = q * (1.f / 65536.f) - m * m;
        mu[d] = m;
        rstd[d] = rsqrtf(var + 1e-5f);
    }
}

// ---------------------------------------------------------------------------
// 3) Fold norm into QKV weights (bf16) + bias correction (fp32). Per batch.
// ---------------------------------------------------------------------------
__global__ __launch_bounds__(256) void fold_kernel(const float* __restrict__ in_w,
                                                   const float* __restrict__ in_b,
                                                   const float* __restrict__ mu,
                                                   const float* __restrict__ rstd,
                                                   u16* __restrict__ Wp,
                                                   float* __restrict__ bprime) {
    int e = blockIdx.x;                // 0..767
    int d = threadIdx.x;
    float m = mu[d];
    float r = rstd[d];
    float w = in_w[e * D_MODEL + d];
    Wp[(size_t)e * D_MODEL + d] = f2b(w * r);
    float contrib = w * r * m;
    for (int off = 32; off; off >>= 1) contrib += __shfl_down(contrib, off);
    __shared__ float rr[4];
    if ((d & 63) == 0) rr[d >> 6] = contrib;
    __syncthreads();
    if (d == 0) bprime[e] = in_b[e] - (rr[0] + rr[1] + rr[2] + rr[3]);
}

// ---------------------------------------------------------------------------
// 4) MFMA GEMM: C[M x 65536] = A[M x 256] * Bt[65536 x 256]^T (+bias,+resid)
//    128x128 tile, 4 waves, 4x4 MFMA 16x16x32 per wave. global_load_lds w/
//    XOR chunk swizzle. 1-D grid, y-fastest decomposition + bijective
//    XCD-chunk swizzle: the YT blocks sharing a B-panel run adjacently on
//    one XCD -> panel re-reads hit that XCD's L2 instead of L3/HBM.
//    PERC: A per-c (c = xx>>3). QSM: yy 0,1 are the q rows -> in-register
//    feature-softmax, write Pq[p][256] bf16.
// ---------------------------------------------------------------------------
template <bool RESID, bool PERC, bool QSM, int YT, typename OT>
__global__ __launch_bounds__(256) void mgemm(const u16* __restrict__ A,
                                             const u16* __restrict__ Bt,
                                             const float* __restrict__ bias,
                                             const float* __restrict__ resid,
                                             OT* __restrict__ Cout,
                                             u16* __restrict__ qout) {
    __shared__ __align__(16) u16 As[128 * BK];   // [m][k] swizzled, 16 KB
    __shared__ __align__(16) u16 Bs[128 * BK];   // [n][k] swizzled, 16 KB
    const int tid  = threadIdx.x;
    const int wave = tid >> 6;
    const int lane = tid & 63;

    // XCD-chunk swizzle (grid % 8 == 0 -> bijective), then y-fastest.
    const int bid = blockIdx.x;
    const int per = (int)gridDim.x >> 3;
    const int lid = (bid & 7) * per + (bid >> 3);
    const int yy = lid % YT;
    const int xx = lid / YT;

    const int m0 = yy * 128;
    const int p0 = xx * 128;
    const int mw = (wave >> 1) * 64;
    const int nw = (wave & 1) * 64;

    const u16* Ab = PERC ? A + ((size_t)(xx >> 3) << 16) : A;

    floatx4 acc[4][4];
#pragma unroll
    for (int i = 0; i < 4; ++i)
#pragma unroll
        for (int j = 0; j < 4; ++j) acc[i][j] = (floatx4){0.f, 0.f, 0.f, 0.f};

    const int srow = lane >> 3;      // 0..7 (row within 8-row group)
    const int schunk = lane & 7;     // 0..7 (16B chunk within 128B row)
    const int q  = lane >> 4;        // quad 0..3
    const int rl = lane & 15;

    for (int s = 0; s < 4; ++s) {
        const int k0 = s * BK;
#pragma unroll
        for (int j = 0; j < 4; ++j) {
            int rbase = wave * 32 + j * 8;            // wave-uniform
            int r = rbase + srow;
            int cg = schunk ^ (r & 7);                // swizzle on global side
            gload_lds16(Ab + ((size_t)(m0 + r) << 8) + k0 + cg * 8, &As[rbase * BK]);
            gload_lds16(Bt + ((size_t)(p0 + r) << 8) + k0 + cg * 8, &Bs[rbase * BK]);
        }
        __syncthreads();   // drains vmcnt before barrier (compiler-inserted)
#pragma unroll
        for (int ks = 0; ks < 2; ++ks) {
            bf16x8 af[4], bf[4];
#pragma unroll
            for (int ti = 0; ti < 4; ++ti) {
                int r = mw + 16 * ti + rl;
                int cp = (ks * 4 + q) ^ (r & 7);
                af[ti] = *(const bf16x8*)&As[r * BK + cp * 8];
            }
#pragma unroll
            for (int tj = 0; tj < 4; ++tj) {
                int r = nw + 16 * tj + rl;
                int cp = (ks * 4 + q) ^ (r & 7);
                bf[tj] = *(const bf16x8*)&Bs[r * BK + cp * 8];
            }
#pragma unroll
            for (int ti = 0; ti < 4; ++ti)
#pragma unroll
                for (int tj = 0; tj < 4; ++tj)
                    acc[ti][tj] = __builtin_amdgcn_mfma_f32_16x16x32_bf16(
                        af[ti], bf[tj], acc[ti][tj], 0, 0, 0);
        }
        __syncthreads();
    }

    // Epilogue. C/D layout: col = lane&15 (n), row = quad*4 + reg (m).
    if (QSM && yy < 2) {
        // q rows: feature-softmax per (head, column). Wave rows = 2 heads.
        float den[2][4] = {{0.f, 0.f, 0.f, 0.f}, {0.f, 0.f, 0.f, 0.f}};
#pragma unroll
        for (int ti = 0; ti < 4; ++ti) {
#pragma unroll
            for (int i = 0; i < 4; ++i) {
                int e = m0 + mw + 16 * ti + 4 * q + i;
                float bv = bias[e];
#pragma unroll
                for (int tj = 0; tj < 4; ++tj) {
                    float ex = __expf(acc[ti][tj][i] + bv);
                    acc[ti][tj][i] = ex;
                    den[ti >> 1][tj] += ex;
                }
            }
        }
#pragma unroll
        for (int hh = 0; hh < 2; ++hh)
#pragma unroll
            for (int tj = 0; tj < 4; ++tj) {
                float dsum = den[hh][tj];
                dsum += __shfl_xor(dsum, 16);
                dsum += __shfl_xor(dsum, 32);
                den[hh][tj] = 1.f / dsum;
            }
#pragma unroll
        for (int tj = 0; tj < 4; ++tj) {
            size_t p = (size_t)(p0 + nw + 16 * tj + rl);
            u16* row = qout + p * D_MODEL + m0 + mw;
#pragma unroll
            for (int ti = 0; ti < 4; ++ti) {
                float inv = den[ti >> 1][tj];
                ushort4 o = make_ushort4(f2b(acc[ti][tj][0] * inv),
                                         f2b(acc[ti][tj][1] * inv),
                                         f2b(acc[ti][tj][2] * inv),
                                         f2b(acc[ti][tj][3] * inv));
                *(ushort4*)(row + 16 * ti + 4 * q) = o;
            }
        }
        return;
    }
#pragma unroll
    for (int ti = 0; ti < 4; ++ti) {
#pragma unroll
        for (int i = 0; i < 4; ++i) {
            int e = m0 + mw + 16 * ti + 4 * q + i;
            float bv = bias[e];
            size_t rowbase = (size_t)e * P_LEN + p0 + nw;
#pragma unroll
            for (int tj = 0; tj < 4; ++tj) {
                size_t addr = rowbase + 16 * tj + rl;
                float v = acc[ti][tj][i] + bv;
                if (RESID) v += resid[addr];
                stc(Cout + addr, v);
            }
        }
    }
}

// ---------------------------------------------------------------------------
// 5) ctx kernel (single-pass): per (c,h): stage UNNORMALIZED e^k and v into
//    LDS (rows padded to 264 u16), accumulate per-row sums of e^k in regs
//    during staging (width-32 shuffle reduce at end), MFMA 16x16x32 over
//    K=1024 in 4 chunks, normalize by scale/(s*1024) in the fp32 epilogue.
// ---------------------------------------------------------------------------
__global__ __launch_bounds__(256) void ctx_kernel(const u16* __restrict__ qkv,
                                                  float* __restrict__ ctx) {
    int bid = blockIdx.x;              // 0..511
    int c = bid >> 3, h = bid & 7;
    int tid = threadIdx.x;
    size_t colbase = (size_t)c * TDIM;
    const u16* kb = qkv + (size_t)(D_MODEL + h * FDIM) * P_LEN + colbase;
    const u16* vb = qkv + (size_t)(2 * D_MODEL + h * FDIM) * P_LEN + colbase;

    __shared__ float ssum[32];
    __shared__ __align__(16) u16 ekt[32 * 264];
    __shared__ __align__(16) u16 vsb[32 * 264];

    const int lane = tid & 63;
    const int wave = tid >> 6;
    const int rl = lane & 15, q = lane >> 4;
    const int mi = wave >> 1, ni = wave & 1;
    const int o  = tid & 31;           // 16B chunk within 512B row-chunk
    const int r8 = tid >> 5;           // 0..7
    floatx4 acc = {0.f, 0.f, 0.f, 0.f};
    float psum[4] = {0.f, 0.f, 0.f, 0.f};   // per-pass partial e^k sums

    for (int ch = 0; ch < 4; ++ch) {
        int t0 = ch * 256;
        if (ch) __syncthreads();       // protect LDS before restaging
#pragma unroll
        for (int pass = 0; pass < 4; ++pass) {
            int r = pass * 8 + r8;
            uint4 u = *((const uint4*)(kb + (size_t)r * P_LEN + t0) + o);
            uint4 w = *((const uint4*)(vb + (size_t)r * P_LEN + t0) + o);
            float e0 = __expf(b2f_lo(u.x)), e1 = __expf(b2f_hi(u.x));
            float e2 = __expf(b2f_lo(u.y)), e3 = __expf(b2f_hi(u.y));
            float e4 = __expf(b2f_lo(u.z)), e5 = __expf(b2f_hi(u.z));
            float e6 = __expf(b2f_lo(u.w)), e7 = __expf(b2f_hi(u.w));
            psum[pass] += (e0 + e1) + (e2 + e3) + (e4 + e5) + (e6 + e7);
            uint4 E;
            E.x = pack2(e0, e1);
            E.y = pack2(e2, e3);
            E.z = pack2(e4, e5);
            E.w = pack2(e6, e7);
            *(uint4*)&ekt[r * 264 + o * 8] = E;
            *(uint4*)&vsb[r * 264 + o * 8] = w;
        }
        __syncthreads();
#pragma unroll
        for (int ks = 0; ks < 8; ++ks) {
            bf16x8 a  = *(const bf16x8*)&ekt[(16 * mi + rl) * 264 + ks * 32 + q * 8];
            bf16x8 bv = *(const bf16x8*)&vsb[(16 * ni + rl) * 264 + ks * 32 + q * 8];
            acc = __builtin_amdgcn_mfma_f32_16x16x32_bf16(a, bv, acc, 0, 0, 0);
        }
    }

    // row sums: threads {r8*32 + o, o=0..31} jointly own rows r = pass*8+r8
#pragma unroll
    for (int pass = 0; pass < 4; ++pass) {
        float s = psum[pass];
        for (int off = 16; off; off >>= 1) s += __shfl_down(s, off, 32);
        if (o == 0) ssum[pass * 8 + r8] = s;
    }
    __syncthreads();

    // C/D layout: col = lane&15 (n = v), row = 4q + i (m = k)
    float* co = ctx + (size_t)bid * 1024;
#pragma unroll
    for (int i = 0; i < 4; ++i) {
        int krow = 16 * mi + 4 * q + i;
        float iv = 0.17677669529663687f / (ssum[krow] * 1024.f);
        co[krow * 32 + 16 * ni + rl] = acc[i] * iv;
    }
}

// ---------------------------------------------------------------------------
// 6) Fold ctx into out-projection: W2'_c[e][h*32+k] = sum_v W2[e][h*32+v] *
//    ctx[c][h][k][v], bf16 out. Grid (64 c, 2 e-halves).
// ---------------------------------------------------------------------------
__global__ __launch_bounds__(256) void wfold_kernel(const float* __restrict__ w2,
                                                    const float* __restrict__ ctx,
                                                    u16* __restrict__ w2p) {
    __shared__ float cs[8192];         // ctx[c][8][32][32]
    int c = blockIdx.x;
    int tid = threadIdx.x;
    const float4* cb = (const float4*)(ctx + (size_t)c * 8192);
#pragma unroll
    for (int i = 0; i < 8; ++i)
        ((float4*)cs)[i * 256 + tid] = cb[i * 256 + tid];
    __syncthreads();
    int e = blockIdx.y * 128 + (tid >> 1);
    int hh = tid & 1;
    const float* wrow = w2 + (size_t)e * 256;
    u16* orow = w2p + ((size_t)c << 16) + (size_t)e * 256;
#pragma unroll
    for (int hi = 0; hi < 4; ++hi) {
        int h = hh * 4 + hi;
        float w[32];
#pragma unroll
        for (int v = 0; v < 8; ++v) {
            float4 t4 = *(const float4*)&wrow[h * 32 + v * 4];
            w[v * 4 + 0] = t4.x; w[v * 4 + 1] = t4.y;
            w[v * 4 + 2] = t4.z; w[v * 4 + 3] = t4.w;
        }
        const float* chp = cs + h * 1024;
#pragma unroll
        for (int kc = 0; kc < 4; ++kc) {
            union { u16 u[8]; uint4 v4; } pk;
#pragma unroll
            for (int ki = 0; ki < 8; ++ki) {
                const float* ck = chp + (kc * 8 + ki) * 32;
                float acc = 0.f;
#pragma unroll
                for (int v = 0; v < 32; v += 4) {
                    float4 c4 = *(const float4*)&ck[v];
                    acc += w[v] * c4.x + w[v + 1] * c4.y
                         + w[v + 2] * c4.z + w[v + 3] * c4.w;
                }
                pk.u[ki] = f2b(acc);
            }
            *(uint4*)(orow + h * 32 + kc * 8) = pk.v4;
        }
    }
}

// ---------------------------------------------------------------------------
// Workspace layout (bytes) — round-4 verified serial layout:
//   mu      [256] f32             @ 0           (1024)  per-batch
//   rstd    [256] f32             @ 1024        (1024)  per-batch
//   Wp      [1536*256] bf16       @ 4096        (786432)
//   bprime  [1536] f32            @ 790528      (6144)
//   tbuf    [65536*256] bf16      @ 796672      (33554432)  xbT; after mgemm1
//     ctxb = tbuf + 0    (2 MB fp32 [64][8][32][32])      tbuf is dead ->
//     w2p  = tbuf + 2 MB (8 MB bf16 [64][256][256])       ctx/w2p alias it
//   qkvb    [768*65536] bf16      @ 34351104    (100663296)
//     Pq   = qkvb first 33.5 MB:  [65536][256] bf16 (q region, written by
//            mgemm1's QSM epilogue); k,v rows 256..767 as [e][p].
//     pscr = ws + 132917248 (1 MB), qscr = ws + 133965824 (1 MB):
//            alias the LAST 2 MB of qkvb — dead during transpose/reduce/fold,
//            rewritten by mgemm1 afterwards (in-stream order).
// total = 135014400 bytes
// ---------------------------------------------------------------------------
extern "C" void kernel_launch(void* const* d_in, const int* in_sizes, int n_in,
                              void* d_out, int out_size, void* d_ws, size_t ws_size,
                              hipStream_t stream) {
    const float* x     = (const float*)d_in[0];
    const float* in_w  = (const float*)d_in[1];
    const float* in_b  = (const float*)d_in[2];
    const float* out_w = (const float*)d_in[3];
    const float* out_b = (const float*)d_in[4];
    float* out = (float*)d_out;

    char* ws = (char*)d_ws;
    float* mu     = (float*)(ws);
    float* rstd   = (float*)(ws + 1024);
    u16*   Wp     = (u16*)(ws + 4096);
    float* bprime = (float*)(ws + 790528);
    u16*   tbuf   = (u16*)(ws + 796672);
    float* ctxb   = (float*)(ws + 796672);                 // aliases dead tbuf
    u16*   w2p    = (u16*)(ws + 796672 + 2097152);         // aliases dead tbuf
    u16*   qkvb   = (u16*)(ws + 34351104);
    float* pscr   = (float*)(ws + 132917248);              // aliases qkvb tail
    float* qscr   = (float*)(ws + 133965824);              // aliases qkvb tail

    for (int b = 0; b < 2; ++b) {
        const float* xb = x + (size_t)b * D_MODEL * P_LEN;
        transpose_x<<<dim3(1024, 4), 256, 0, stream>>>(xb, tbuf, pscr, qscr);
        reduce_stats<<<256, 64, 0, stream>>>(pscr, qscr, mu, rstd);
        fold_kernel<<<K3, 256, 0, stream>>>(in_w, in_b, mu, rstd,
                                            Wp + (size_t)b * K3 * D_MODEL,
                                            bprime + b * K3);
        mgemm<false, false, true, 6, u16><<<3072, 256, 0, stream>>>(
            Wp + (size_t)b * K3 * D_MODEL, tbuf, bprime + b * K3, nullptr,
            qkvb, qkvb /*Pq*/);
        ctx_kernel<<<512, 256, 0, stream>>>(qkvb, ctxb);
        wfold_kernel<<<dim3(64, 2), 256, 0, stream>>>(out_w, ctxb, w2p);
        mgemm<true, true, false, 2, float><<<1024, 256, 0, stream>>>(
            w2p, qkvb /*Pq*/, out_b, xb, out + (size_t)b * D_MODEL * P_LEN,
            nullptr);
    }
}

// Round 7
// 517.153 us; speedup vs baseline: 1.2986x; 1.2986x over previous
//
#include <hip/hip_runtime.h>
#include <stdint.h>

// Problem constants (B=2, D_MODEL=256, C=64, T=1024, H=8, F=32)
// Inputs fp32, output fp32. Intermediates bf16. GEMMs on MFMA bf16.
#define D_MODEL 256
#define TDIM    1024
#define NHEADS  8
#define FDIM    32
#define P_LEN   65536      // C*T positions per batch
#define K3      768        // 3*D_MODEL
#define BK      64         // K-tile per LDS stage

using u16 = unsigned short;

typedef __bf16 bf16x8 __attribute__((ext_vector_type(8)));
typedef float  floatx4 __attribute__((ext_vector_type(4)));

__device__ __forceinline__ float b2f_lo(uint32_t u) {
    union { float f; uint32_t i; } v; v.i = u << 16; return v.f;
}
__device__ __forceinline__ float b2f_hi(uint32_t u) {
    union { float f; uint32_t i; } v; v.i = u & 0xffff0000u; return v.f;
}
__device__ __forceinline__ u16 f2b(float f) {
    union { float f; uint32_t i; } v; v.f = f;
    uint32_t i = v.i;
    uint32_t r = i + 0x7fffu + ((i >> 16) & 1u);   // RNE
    return (u16)(r >> 16);
}
__device__ __forceinline__ uint32_t pack2(float lo, float hi) {
    return ((uint32_t)f2b(hi) << 16) | (uint32_t)f2b(lo);
}

// async global->LDS, 16B per lane; lds base must be wave-uniform, lane i
// lands at base + i*16 (guide §5 / m97 / m104).
__device__ __forceinline__ void gload_lds16(const u16* g, u16* l) {
    __builtin_amdgcn_global_load_lds((const __attribute__((address_space(1))) void*)g,
                                     (__attribute__((address_space(3))) void*)l,
                                     16, 0, 0);
}

__device__ __forceinline__ void stc(u16* p, float v) { *p = f2b(v); }
__device__ __forceinline__ void stc(float* p, float v) { *p = v; }

// ---------------------------------------------------------------------------
// 1) Transpose + bf16 convert + InstanceNorm partial stats:
//    x[d][p] fp32 -> xt[p][d] bf16 (one batch); per-(d, blockIdx.x) partial
//    Sum/SumSq written contention-free to pscr/qscr[d][1024].
// ---------------------------------------------------------------------------
__global__ __launch_bounds__(256) void transpose_x(const float* __restrict__ x,
                                                   u16* __restrict__ xt,
                                                   float* __restrict__ pscr,
                                                   float* __restrict__ qscr) {
    __shared__ float tile[64][65];
    int p0 = blockIdx.x * 64;
    int d0 = blockIdx.y * 64;
    int tid = threadIdx.x;
    int dr = tid >> 4;            // 0..15
    int pc = (tid & 15) * 4;      // 0..60
#pragma unroll
    for (int it = 0; it < 4; ++it) {
        int d = it * 16 + dr;
        float4 v = *(const float4*)&x[(size_t)(d0 + d) * P_LEN + p0 + pc];
        tile[pc + 0][d] = v.x;
        tile[pc + 1][d] = v.y;
        tile[pc + 2][d] = v.z;
        tile[pc + 3][d] = v.w;
        // fused stats: 16 lanes (same dr) hold this row's 64 p-values
        float s = v.x + v.y + v.z + v.w;
        float sq = v.x * v.x + v.y * v.y + v.z * v.z + v.w * v.w;
#pragma unroll
        for (int off = 8; off; off >>= 1) {
            s  += __shfl_down(s, off, 16);
            sq += __shfl_down(sq, off, 16);
        }
        if ((tid & 15) == 0) {
            pscr[(size_t)(d0 + d) * 1024 + blockIdx.x] = s;
            qscr[(size_t)(d0 + d) * 1024 + blockIdx.x] = sq;
        }
    }
    __syncthreads();
    int pr = tid >> 3;            // 0..31
    int dc = (tid & 7) * 8;       // 0..56
#pragma unroll
    for (int it = 0; it < 2; ++it) {
        int p = it * 32 + pr;
        ushort4 o0 = make_ushort4(f2b(tile[p][dc + 0]), f2b(tile[p][dc + 1]),
                                  f2b(tile[p][dc + 2]), f2b(tile[p][dc + 3]));
        ushort4 o1 = make_ushort4(f2b(tile[p][dc + 4]), f2b(tile[p][dc + 5]),
                                  f2b(tile[p][dc + 6]), f2b(tile[p][dc + 7]));
        u16* dst = xt + (size_t)(p0 + p) * D_MODEL + d0 + dc;
        *(ushort4*)dst = o0;
        *(ushort4*)(dst + 4) = o1;
    }
}

// ---------------------------------------------------------------------------
// 2) Reduce partials -> mu/rstd. One wave per d, coalesced float4 reads.
// ---------------------------------------------------------------------------
__global__ __launch_bounds__(64) void reduce_stats(const float* __restrict__ pscr,
                                                   const float* __restrict__ qscr,
                                                   float* __restrict__ mu,
                                                   float* __restrict__ rstd) {
    int d = blockIdx.x, t = threadIdx.x;
    const float4* ps = (const float4*)(pscr + (size_t)d * 1024);
    const float4* qs = (const float4*)(qscr + (size_t)d * 1024);
    float s = 0.f, q = 0.f;
#pragma unroll
    for (int i = 0; i < 4; ++i) {
        float4 a = ps[t + i * 64]; s += a.x + a.y + a.z + a.w;
        float4 b = qs[t + i * 64]; q += b.x + b.y + b.z + b.w;
    }
    for (int off = 32; off; off >>= 1) {
        s += __shfl_down(s, off);
        q += __shfl_down(q, off);
    }
    if (t == 0) {
        float m = s * (1.f / 65536.f);
        float var = q * (1.f / 65536.f) - m * m;
        mu[d] = m;
        rstd[d] = rsqrtf(var + 1e-5f);
    }
}

// ---------------------------------------------------------------------------
// 3) Fold norm into QKV weights (bf16) + bias correction (fp32). Per batch.
// ---------------------------------------------------------------------------
__global__ __launch_bounds__(256) void fold_kernel(const float* __restrict__ in_w,
                                                   const float* __restrict__ in_b,
                                                   const float* __restrict__ mu,
                                                   const float* __restrict__ rstd,
                                                   u16* __restrict__ Wp,
                                                   float* __restrict__ bprime) {
    int e = blockIdx.x;                // 0..767
    int d = threadIdx.x;
    float m = mu[d];
    float r = rstd[d];
    float w = in_w[e * D_MODEL + d];
    Wp[(size_t)e * D_MODEL + d] = f2b(w * r);
    float contrib = w * r * m;
    for (int off = 32; off; off >>= 1) contrib += __shfl_down(contrib, off);
    __shared__ float rr[4];
    if ((d & 63) == 0) rr[d >> 6] = contrib;
    __syncthreads();
    if (d == 0) bprime[e] = in_b[e] - (rr[0] + rr[1] + rr[2] + rr[3]);
}

// ---------------------------------------------------------------------------
// 3b) One-time fp32 -> bf16 convert of W2 (256x256).
// ---------------------------------------------------------------------------
__global__ __launch_bounds__(256) void cvt_w(const float* __restrict__ w,
                                             u16* __restrict__ o) {
    int i = blockIdx.x * 256 + threadIdx.x;
    o[i] = f2b(w[i]);
}

// ---------------------------------------------------------------------------
// 4) MFMA GEMM: C[M x 65536] = A[M x 256] * Bt[65536 x 256]^T (+bias,+resid)
//    128x128 tile, 4 waves, 4x4 MFMA 16x16x32 per wave. global_load_lds w/
//    XOR chunk swizzle. PERC: A per-c (c = blockIdx.x>>3). QSM: y-tiles 0,1
//    are the q rows -> in-register feature-softmax, write Pq[p][256] bf16.
//    (round-4 verified configuration, 2-D grid, no block swizzle)
// ---------------------------------------------------------------------------
template <bool RESID, bool PERC, bool QSM, typename OT>
__global__ __launch_bounds__(256) void mgemm(const u16* __restrict__ A,
                                             const u16* __restrict__ Bt,
                                             const float* __restrict__ bias,
                                             const float* __restrict__ resid,
                                             OT* __restrict__ Cout,
                                             u16* __restrict__ qout) {
    __shared__ __align__(16) u16 As[128 * BK];   // [m][k] swizzled, 16 KB
    __shared__ __align__(16) u16 Bs[128 * BK];   // [n][k] swizzled, 16 KB
    const int tid  = threadIdx.x;
    const int wave = tid >> 6;
    const int lane = tid & 63;
    const int m0 = blockIdx.y * 128;
    const int p0 = blockIdx.x * 128;
    const int mw = (wave >> 1) * 64;
    const int nw = (wave & 1) * 64;

    const u16* Ab = PERC ? A + ((size_t)(blockIdx.x >> 3) << 16) : A;

    floatx4 acc[4][4];
#pragma unroll
    for (int i = 0; i < 4; ++i)
#pragma unroll
        for (int j = 0; j < 4; ++j) acc[i][j] = (floatx4){0.f, 0.f, 0.f, 0.f};

    const int srow = lane >> 3;      // 0..7 (row within 8-row group)
    const int schunk = lane & 7;     // 0..7 (16B chunk within 128B row)
    const int q  = lane >> 4;        // quad 0..3
    const int rl = lane & 15;

    for (int s = 0; s < 4; ++s) {
        const int k0 = s * BK;
#pragma unroll
        for (int j = 0; j < 4; ++j) {
            int rbase = wave * 32 + j * 8;            // wave-uniform
            int r = rbase + srow;
            int cg = schunk ^ (r & 7);                // swizzle on global side
            gload_lds16(Ab + ((size_t)(m0 + r) << 8) + k0 + cg * 8, &As[rbase * BK]);
            gload_lds16(Bt + ((size_t)(p0 + r) << 8) + k0 + cg * 8, &Bs[rbase * BK]);
        }
        __syncthreads();   // drains vmcnt before barrier (compiler-inserted)
#pragma unroll
        for (int ks = 0; ks < 2; ++ks) {
            bf16x8 af[4], bf[4];
#pragma unroll
            for (int ti = 0; ti < 4; ++ti) {
                int r = mw + 16 * ti + rl;
                int cp = (ks * 4 + q) ^ (r & 7);
                af[ti] = *(const bf16x8*)&As[r * BK + cp * 8];
            }
#pragma unroll
            for (int tj = 0; tj < 4; ++tj) {
                int r = nw + 16 * tj + rl;
                int cp = (ks * 4 + q) ^ (r & 7);
                bf[tj] = *(const bf16x8*)&Bs[r * BK + cp * 8];
            }
#pragma unroll
            for (int ti = 0; ti < 4; ++ti)
#pragma unroll
                for (int tj = 0; tj < 4; ++tj)
                    acc[ti][tj] = __builtin_amdgcn_mfma_f32_16x16x32_bf16(
                        af[ti], bf[tj], acc[ti][tj], 0, 0, 0);
        }
        __syncthreads();
    }

    // Epilogue. C/D layout: col = lane&15 (n), row = quad*4 + reg (m).
    if (QSM && blockIdx.y < 2) {
        // q rows: feature-softmax per (head, column). Wave rows = 2 heads.
        float den[2][4] = {{0.f, 0.f, 0.f, 0.f}, {0.f, 0.f, 0.f, 0.f}};
#pragma unroll
        for (int ti = 0; ti < 4; ++ti) {
#pragma unroll
            for (int i = 0; i < 4; ++i) {
                int e = m0 + mw + 16 * ti + 4 * q + i;
                float bv = bias[e];
#pragma unroll
                for (int tj = 0; tj < 4; ++tj) {
                    float ex = __expf(acc[ti][tj][i] + bv);
                    acc[ti][tj][i] = ex;
                    den[ti >> 1][tj] += ex;
                }
            }
        }
#pragma unroll
        for (int hh = 0; hh < 2; ++hh)
#pragma unroll
            for (int tj = 0; tj < 4; ++tj) {
                float dsum = den[hh][tj];
                dsum += __shfl_xor(dsum, 16);
                dsum += __shfl_xor(dsum, 32);
                den[hh][tj] = 1.f / dsum;
            }
#pragma unroll
        for (int tj = 0; tj < 4; ++tj) {
            size_t p = (size_t)(p0 + nw + 16 * tj + rl);
            u16* row = qout + p * D_MODEL + m0 + mw;
#pragma unroll
            for (int ti = 0; ti < 4; ++ti) {
                float inv = den[ti >> 1][tj];
                ushort4 o = make_ushort4(f2b(acc[ti][tj][0] * inv),
                                         f2b(acc[ti][tj][1] * inv),
                                         f2b(acc[ti][tj][2] * inv),
                                         f2b(acc[ti][tj][3] * inv));
                *(ushort4*)(row + 16 * ti + 4 * q) = o;
            }
        }
        return;
    }
#pragma unroll
    for (int ti = 0; ti < 4; ++ti) {
#pragma unroll
        for (int i = 0; i < 4; ++i) {
            int e = m0 + mw + 16 * ti + 4 * q + i;
            float bv = bias[e];
            size_t rowbase = (size_t)e * P_LEN + p0 + nw;
#pragma unroll
            for (int tj = 0; tj < 4; ++tj) {
                size_t addr = rowbase + 16 * tj + rl;
                float v = acc[ti][tj][i] + bv;
                if (RESID) v += resid[addr];
                stc(Cout + addr, v);
            }
        }
    }
}

// ---------------------------------------------------------------------------
// 5) ctx kernel (single-pass): per (c,h): stage UNNORMALIZED e^k and v into
//    LDS (rows padded to 264 u16), accumulate per-row sums of e^k in regs
//    during staging (width-32 shuffle reduce at end), MFMA 16x16x32 over
//    K=1024 in 4 chunks, normalize by scale/(s*1024) in the epilogue.
//    Output now bf16 [c][h][k][v] (v contiguous) for the MFMA wfold.
// ---------------------------------------------------------------------------
__global__ __launch_bounds__(256) void ctx_kernel(const u16* __restrict__ qkv,
                                                  u16* __restrict__ ctx16) {
    int bid = blockIdx.x;              // 0..511
    int c = bid >> 3, h = bid & 7;
    int tid = threadIdx.x;
    size_t colbase = (size_t)c * TDIM;
    const u16* kb = qkv + (size_t)(D_MODEL + h * FDIM) * P_LEN + colbase;
    const u16* vb = qkv + (size_t)(2 * D_MODEL + h * FDIM) * P_LEN + colbase;

    __shared__ float ssum[32];
    __shared__ __align__(16) u16 ekt[32 * 264];
    __shared__ __align__(16) u16 vsb[32 * 264];

    const int lane = tid & 63;
    const int wave = tid >> 6;
    const int rl = lane & 15, q = lane >> 4;
    const int mi = wave >> 1, ni = wave & 1;
    const int o  = tid & 31;           // 16B chunk within 512B row-chunk
    const int r8 = tid >> 5;           // 0..7
    floatx4 acc = {0.f, 0.f, 0.f, 0.f};
    float psum[4] = {0.f, 0.f, 0.f, 0.f};   // per-pass partial e^k sums

    for (int ch = 0; ch < 4; ++ch) {
        int t0 = ch * 256;
        if (ch) __syncthreads();       // protect LDS before restaging
#pragma unroll
        for (int pass = 0; pass < 4; ++pass) {
            int r = pass * 8 + r8;
            uint4 u = *((const uint4*)(kb + (size_t)r * P_LEN + t0) + o);
            uint4 w = *((const uint4*)(vb + (size_t)r * P_LEN + t0) + o);
            float e0 = __expf(b2f_lo(u.x)), e1 = __expf(b2f_hi(u.x));
            float e2 = __expf(b2f_lo(u.y)), e3 = __expf(b2f_hi(u.y));
            float e4 = __expf(b2f_lo(u.z)), e5 = __expf(b2f_hi(u.z));
            float e6 = __expf(b2f_lo(u.w)), e7 = __expf(b2f_hi(u.w));
            psum[pass] += (e0 + e1) + (e2 + e3) + (e4 + e5) + (e6 + e7);
            uint4 E;
            E.x = pack2(e0, e1);
            E.y = pack2(e2, e3);
            E.z = pack2(e4, e5);
            E.w = pack2(e6, e7);
            *(uint4*)&ekt[r * 264 + o * 8] = E;
            *(uint4*)&vsb[r * 264 + o * 8] = w;
        }
        __syncthreads();
#pragma unroll
        for (int ks = 0; ks < 8; ++ks) {
            bf16x8 a  = *(const bf16x8*)&ekt[(16 * mi + rl) * 264 + ks * 32 + q * 8];
            bf16x8 bv = *(const bf16x8*)&vsb[(16 * ni + rl) * 264 + ks * 32 + q * 8];
            acc = __builtin_amdgcn_mfma_f32_16x16x32_bf16(a, bv, acc, 0, 0, 0);
        }
    }

    // row sums: threads {r8*32 + o, o=0..31} jointly own rows r = pass*8+r8
#pragma unroll
    for (int pass = 0; pass < 4; ++pass) {
        float s = psum[pass];
        for (int off = 16; off; off >>= 1) s += __shfl_down(s, off, 32);
        if (o == 0) ssum[pass * 8 + r8] = s;
    }
    __syncthreads();

    // C/D layout: col = lane&15 (n = v), row = 4q + i (m = k)
    u16* co = ctx16 + (size_t)bid * 1024;
#pragma unroll
    for (int i = 0; i < 4; ++i) {
        int krow = 16 * mi + 4 * q + i;
        float iv = 0.17677669529663687f / (ssum[krow] * 1024.f);
        co[krow * 32 + 16 * ni + rl] = f2b(acc[i] * iv);
    }
}

// ---------------------------------------------------------------------------
// 6) MFMA wfold: W2'_c[e][h*32+k] = sum_v W2[e][h*32+v] * ctx[c][h][k][v].
//    Pure-register MFMA 16x16x32 (K = v = 32), A/B straight from global
//    (both L2-resident: W2b 128 KB, ctx16 1 MB). No LDS, no barriers.
//    Grid (64 c, 4 e-quarters) x 4 waves; wave = one 16-row e-tile.
// ---------------------------------------------------------------------------
__global__ __launch_bounds__(256) void wfold2(const u16* __restrict__ w2b,
                                              const u16* __restrict__ ctx16,
                                              u16* __restrict__ w2p) {
    const int c = blockIdx.x;
    const int lane = threadIdx.x & 63;
    const int wave = threadIdx.x >> 6;
    const int m0 = blockIdx.y * 64 + wave * 16;       // e-tile base
    const int rl = lane & 15, q = lane >> 4;
    const u16* cb = ctx16 + ((size_t)c << 13);        // c * 8192
    u16* ob = w2p + ((size_t)c << 16);
#pragma unroll
    for (int h = 0; h < 8; ++h) {
        // A-frag: lane(rl,q) = W2[e = m0+rl][h*32 + q*8 .. +7]
        bf16x8 af = *(const bf16x8*)&w2b[(size_t)(m0 + rl) * 256 + h * 32 + q * 8];
#pragma unroll
        for (int nt = 0; nt < 2; ++nt) {
            // B-frag: lane(rl,q) = ctx[c][h][k = nt*16+rl][v = q*8 .. +7]
            bf16x8 bf = *(const bf16x8*)&cb[h * 1024 + (nt * 16 + rl) * 32 + q * 8];
            floatx4 acc = {0.f, 0.f, 0.f, 0.f};
            acc = __builtin_amdgcn_mfma_f32_16x16x32_bf16(af, bf, acc, 0, 0, 0);
            // D: col = rl (k), row = 4q+i (e)
            u16* ocol = ob + h * 32 + nt * 16 + rl;
#pragma unroll
            for (int i = 0; i < 4; ++i)
                ocol[(size_t)(m0 + 4 * q + i) * 256] = f2b(acc[i]);
        }
    }
}

// ---------------------------------------------------------------------------
// Workspace layout (bytes) — round-4 verified layout + Wp2 appended:
//   mu      [256] f32             @ 0           (1024)  per-batch
//   rstd    [256] f32             @ 1024        (1024)  per-batch
//   Wp      [1536*256] bf16       @ 4096        (786432)
//   bprime  [1536] f32            @ 790528      (6144)
//   tbuf    [65536*256] bf16      @ 796672      (33554432)  xbT; after mgemm1
//     ctx16 = tbuf + 0    (1 MB bf16 [64][8][32][32])     tbuf is dead ->
//     w2p   = tbuf + 2 MB (8 MB bf16 [64][256][256])      ctx/w2p alias it
//   qkvb    [768*65536] bf16      @ 34351104    (100663296)
//     Pq   = qkvb first 33.5 MB:  [65536][256] bf16 (q region, written by
//            mgemm1's QSM epilogue); k,v rows 256..767 as [e][p].
//     pscr = ws + 132917248 (1 MB), qscr = ws + 133965824 (1 MB):
//            alias the LAST 2 MB of qkvb — dead during transpose/reduce/fold,
//            rewritten by mgemm1 afterwards (in-stream order).
//   Wp2     [256*256] bf16        @ 135014400   (131072)
// total = 135145472 bytes
// ---------------------------------------------------------------------------
extern "C" void kernel_launch(void* const* d_in, const int* in_sizes, int n_in,
                              void* d_out, int out_size, void* d_ws, size_t ws_size,
                              hipStream_t stream) {
    const float* x     = (const float*)d_in[0];
    const float* in_w  = (const float*)d_in[1];
    const float* in_b  = (const float*)d_in[2];
    const float* out_w = (const float*)d_in[3];
    const float* out_b = (const float*)d_in[4];
    float* out = (float*)d_out;

    char* ws = (char*)d_ws;
    float* mu     = (float*)(ws);
    float* rstd   = (float*)(ws + 1024);
    u16*   Wp     = (u16*)(ws + 4096);
    float* bprime = (float*)(ws + 790528);
    u16*   tbuf   = (u16*)(ws + 796672);
    u16*   ctx16  = (u16*)(ws + 796672);                   // aliases dead tbuf
    u16*   w2p    = (u16*)(ws + 796672 + 2097152);         // aliases dead tbuf
    u16*   qkvb   = (u16*)(ws + 34351104);
    float* pscr   = (float*)(ws + 132917248);              // aliases qkvb tail
    float* qscr   = (float*)(ws + 133965824);              // aliases qkvb tail
    u16*   Wp2    = (u16*)(ws + 135014400);

    cvt_w<<<256, 256, 0, stream>>>(out_w, Wp2);

    for (int b = 0; b < 2; ++b) {
        const float* xb = x + (size_t)b * D_MODEL * P_LEN;
        transpose_x<<<dim3(1024, 4), 256, 0, stream>>>(xb, tbuf, pscr, qscr);
        reduce_stats<<<256, 64, 0, stream>>>(pscr, qscr, mu, rstd);
        fold_kernel<<<K3, 256, 0, stream>>>(in_w, in_b, mu, rstd,
                                            Wp + (size_t)b * K3 * D_MODEL,
                                            bprime + b * K3);
        mgemm<false, false, true, u16><<<dim3(512, 6), 256, 0, stream>>>(
            Wp + (size_t)b * K3 * D_MODEL, tbuf, bprime + b * K3, nullptr,
            qkvb, qkvb /*Pq*/);
        ctx_kernel<<<512, 256, 0, stream>>>(qkvb, ctx16);
        wfold2<<<dim3(64, 4), 256, 0, stream>>>(Wp2, ctx16, w2p);
        mgemm<true, true, false, float><<<dim3(512, 2), 256, 0, stream>>>(
            w2p, qkvb /*Pq*/, out_b, xb, out + (size_t)b * D_MODEL * P_LEN,
            nullptr);
    }
}